// Round 5
// baseline (139.777 us; speedup 1.0000x reference)
//
#include <hip/hip_runtime.h>
#include <math.h>

#define HF 37
#define WF 50
#define CC 512
#define POOLD 7
#define SAMPD 14

typedef float  nfloat4 __attribute__((ext_vector_type(4)));
typedef _Float16 half8 __attribute__((ext_vector_type(8)));

struct f8 { float v[8]; };

__device__ __forceinline__ f8 cvt8(half8 h) {
    f8 r;
    #pragma unroll
    for (int k = 0; k < 8; ++k) r.v[k] = (float)h[k];
    return r;
}
__device__ __forceinline__ f8 lerp8(const f8& a, const f8& b, float t) {
    f8 r;
    #pragma unroll
    for (int k = 0; k < 8; ++k) r.v[k] = a.v[k] + t * (b.v[k] - a.v[k]);
    return r;
}
__device__ __forceinline__ f8 max8(const f8& a, const f8& b) {
    f8 r;
    #pragma unroll
    for (int k = 0; k < 8; ++k) r.v[k] = fmaxf(a.v[k], b.v[k]);
    return r;
}
__device__ __forceinline__ void store_nt8(float* p, const f8& m) {
    nfloat4 a, b;
    a.x = m.v[0]; a.y = m.v[1]; a.z = m.v[2]; a.w = m.v[3];
    b.x = m.v[4]; b.y = m.v[5]; b.z = m.v[6]; b.w = m.v[7];
    __builtin_nontemporal_store(a, (nfloat4*)p);
    __builtin_nontemporal_store(b, (nfloat4*)(p + 4));
}

// ---- fp32 -> fp16 feature compression (1.9 MB into d_ws) --------------------
__global__ __launch_bounds__(256) void cvt_kernel(const float* __restrict__ in,
                                                  _Float16* __restrict__ out,
                                                  int total8) {
    int i = blockIdx.x * blockDim.x + threadIdx.x;
    if (i >= total8) return;
    const float4* p = (const float4*)(in + (size_t)i * 8);
    float4 a = p[0], b = p[1];
    half8 h;
    h[0] = (_Float16)a.x; h[1] = (_Float16)a.y; h[2] = (_Float16)a.z; h[3] = (_Float16)a.w;
    h[4] = (_Float16)b.x; h[5] = (_Float16)b.y; h[6] = (_Float16)b.z; h[7] = (_Float16)b.w;
    *(half8*)(out + (size_t)i * 8) = h;   // plain (cached) store -- we WANT L2 residency
}

// ---- main kernel: fp16 feature reads, fp32 arithmetic -----------------------
// RC (fixed per block): 0 -> both sample rows share one row pair (2 loads);
// 1 -> middle row shared (3 loads); 2 -> general (4 loads).
template <int RC>
__device__ __forceinline__ void loadcol_h(const _Float16* __restrict__ pbase, int col,
                                          int ro0, int ro1, int ro2, int ro3,
                                          float wya, float wyb, f8& va, f8& vb) {
    const _Float16* p = pbase + (size_t)col * CC;
    if (RC == 0) {
        f8 rA = cvt8(*(const half8*)(p + ro0));
        f8 rB = cvt8(*(const half8*)(p + ro1));
        va = lerp8(rA, rB, wya);
        vb = lerp8(rA, rB, wyb);
    } else if (RC == 1) {
        f8 rA = cvt8(*(const half8*)(p + ro0));
        f8 rB = cvt8(*(const half8*)(p + ro1));
        f8 rC = cvt8(*(const half8*)(p + ro3));
        va = lerp8(rA, rB, wya);
        vb = lerp8(rB, rC, wyb);
    } else {
        f8 r0 = cvt8(*(const half8*)(p + ro0));
        f8 r1 = cvt8(*(const half8*)(p + ro1));
        f8 r2 = cvt8(*(const half8*)(p + ro2));
        f8 r3 = cvt8(*(const half8*)(p + ro3));
        va = lerp8(r0, r1, wya);
        vb = lerp8(r2, r3, wyb);
    }
}

template <int RC>
__device__ __forceinline__ void run_row_h(const _Float16* __restrict__ pbase,
                                          float* __restrict__ obase,
                                          float nx1, float nx2,
                                          int ro0, int ro1, int ro2, int ro3,
                                          float wya, float wyb) {
    const float inv = 1.0f / (float)(SAMPD - 1);

    int pcol = -1000, ccol = -1000;
    f8 vap, vbp, vac, vbc;
    f8 m0;
    #pragma unroll
    for (int k = 0; k < 8; ++k) m0.v[k] = -INFINITY;

    // ROLLED loop + column dedup cache (proven best structure).
    #pragma unroll 1
    for (int sx = 0; sx < SAMPD; ++sx) {
        float tx = (float)sx * inv;
        float xs = (nx1 + (nx2 - nx1) * tx) * (float)(WF - 1);
        xs = fminf(fmaxf(xs, 0.0f), (float)(WF - 1));
        float x0f = floorf(xs);
        float wx = xs - x0f;
        int c0 = __builtin_amdgcn_readfirstlane((int)x0f);
        int c1 = min(c0 + 1, WF - 1);

        if (c0 == ccol) {
            pcol = ccol; vap = vac; vbp = vbc;
            loadcol_h<RC>(pbase, c1, ro0, ro1, ro2, ro3, wya, wyb, vac, vbc);
            ccol = c1;
        } else if (c0 != pcol) {
            loadcol_h<RC>(pbase, c0, ro0, ro1, ro2, ro3, wya, wyb, vap, vbp);
            pcol = c0;
            loadcol_h<RC>(pbase, c1, ro0, ro1, ro2, ro3, wya, wyb, vac, vbc);
            ccol = c1;
        }

        f8 sa = lerp8(vap, vac, wx);
        f8 sb = lerp8(vbp, vbc, wx);
        m0 = max8(m0, max8(sa, sb));

        if (sx & 1) {
            store_nt8(obase + (size_t)(sx >> 1) * CC, m0);
            #pragma unroll
            for (int k = 0; k < 8; ++k) m0.v[k] = -INFINITY;
        }
    }
}

// One block per (roi, pooled_row). 64 threads * half8 = 512 channels, one wave.
__global__ __launch_bounds__(64, 8) void roipool_h_kernel(
    const _Float16* __restrict__ hfeat, // [HF, WF, CC] fp16
    const float* __restrict__ rois,     // [N, 4] (x1,y1,x2,y2)
    const int*   __restrict__ im_size,  // [2] (h, w)
    float*       __restrict__ out,      // [N, 7, 7, CC]
    int N)
{
    int bid = blockIdx.x;
    int n   = bid / POOLD;
    int py  = bid - n * POOLD;
    if (n >= N) return;

    float h = (float)im_size[0];
    float w = (float)im_size[1];
    float4 box = *(const float4*)(rois + 4 * n);
    float ny1 = box.y / h, nx1 = box.x / w;
    float ny2 = box.w / h, nx2 = box.z / w;

    const float inv = 1.0f / (float)(SAMPD - 1);

    float tya = (float)(2 * py) * inv;
    float tyb = (float)(2 * py + 1) * inv;
    float ysa = (ny1 + (ny2 - ny1) * tya) * (float)(HF - 1);
    float ysb = (ny1 + (ny2 - ny1) * tyb) * (float)(HF - 1);
    ysa = fminf(fmaxf(ysa, 0.0f), (float)(HF - 1));
    ysb = fminf(fmaxf(ysb, 0.0f), (float)(HF - 1));
    float y0fa = floorf(ysa);
    float y0fb = floorf(ysb);
    float wya = ysa - y0fa;
    float wyb = ysb - y0fb;
    int iya = __builtin_amdgcn_readfirstlane((int)y0fa);
    int iyb = __builtin_amdgcn_readfirstlane((int)y0fb);
    int iya1 = min(iya + 1, HF - 1);
    int iyb1 = min(iyb + 1, HF - 1);
    int ro0 = iya  * (WF * CC);
    int ro1 = iya1 * (WF * CC);
    int ro2 = iyb  * (WF * CC);
    int ro3 = iyb1 * (WF * CC);

    const _Float16* pbase = hfeat + (size_t)threadIdx.x * 8;
    float* obase = out + ((size_t)(n * POOLD + py) * POOLD) * CC + (size_t)threadIdx.x * 8;

    if (ro2 == ro0) {
        run_row_h<0>(pbase, obase, nx1, nx2, ro0, ro1, ro2, ro3, wya, wyb);
    } else if (ro2 == ro1) {
        run_row_h<1>(pbase, obase, nx1, nx2, ro0, ro1, ro2, ro3, wya, wyb);
    } else {
        run_row_h<2>(pbase, obase, nx1, nx2, ro0, ro1, ro2, ro3, wya, wyb);
    }
}

// ---- fp32 fallback (baseline structure) if workspace is unavailable ---------
__device__ __forceinline__ float4 lerp4(float4 a, float4 b, float t) {
    float4 r;
    r.x = a.x + t * (b.x - a.x);
    r.y = a.y + t * (b.y - a.y);
    r.z = a.z + t * (b.z - a.z);
    r.w = a.w + t * (b.w - a.w);
    return r;
}
__device__ __forceinline__ float4 max4(float4 a, float4 b) {
    float4 r;
    r.x = fmaxf(a.x, b.x); r.y = fmaxf(a.y, b.y);
    r.z = fmaxf(a.z, b.z); r.w = fmaxf(a.w, b.w);
    return r;
}
__device__ __forceinline__ void store_nt4(float* p, float4 v) {
    nfloat4 nv; nv.x = v.x; nv.y = v.y; nv.z = v.z; nv.w = v.w;
    __builtin_nontemporal_store(nv, (nfloat4*)p);
}

template <int RC>
__device__ __forceinline__ void loadcol_f(const float* __restrict__ pbase, int col,
                                          int ro0, int ro1, int ro2, int ro3,
                                          float wya, float wyb, float4& va, float4& vb) {
    const float* p = pbase + (size_t)col * CC;
    if (RC == 0) {
        float4 rA = *(const float4*)(p + ro0);
        float4 rB = *(const float4*)(p + ro1);
        va = lerp4(rA, rB, wya); vb = lerp4(rA, rB, wyb);
    } else if (RC == 1) {
        float4 rA = *(const float4*)(p + ro0);
        float4 rB = *(const float4*)(p + ro1);
        float4 rC = *(const float4*)(p + ro3);
        va = lerp4(rA, rB, wya); vb = lerp4(rB, rC, wyb);
    } else {
        float4 r0 = *(const float4*)(p + ro0);
        float4 r1 = *(const float4*)(p + ro1);
        float4 r2 = *(const float4*)(p + ro2);
        float4 r3 = *(const float4*)(p + ro3);
        va = lerp4(r0, r1, wya); vb = lerp4(r2, r3, wyb);
    }
}

template <int RC>
__device__ __forceinline__ void run_row_f(const float* __restrict__ pbase,
                                          float* __restrict__ obase,
                                          float nx1, float nx2,
                                          int ro0, int ro1, int ro2, int ro3,
                                          float wya, float wyb) {
    const float inv = 1.0f / (float)(SAMPD - 1);
    int pcol = -1000, ccol = -1000;
    float4 vap, vbp, vac, vbc;
    float4 m0 = make_float4(-INFINITY, -INFINITY, -INFINITY, -INFINITY);
    #pragma unroll 1
    for (int sx = 0; sx < SAMPD; ++sx) {
        float tx = (float)sx * inv;
        float xs = (nx1 + (nx2 - nx1) * tx) * (float)(WF - 1);
        xs = fminf(fmaxf(xs, 0.0f), (float)(WF - 1));
        float x0f = floorf(xs);
        float wx = xs - x0f;
        int c0 = __builtin_amdgcn_readfirstlane((int)x0f);
        int c1 = min(c0 + 1, WF - 1);
        if (c0 == ccol) {
            pcol = ccol; vap = vac; vbp = vbc;
            loadcol_f<RC>(pbase, c1, ro0, ro1, ro2, ro3, wya, wyb, vac, vbc);
            ccol = c1;
        } else if (c0 != pcol) {
            loadcol_f<RC>(pbase, c0, ro0, ro1, ro2, ro3, wya, wyb, vap, vbp);
            pcol = c0;
            loadcol_f<RC>(pbase, c1, ro0, ro1, ro2, ro3, wya, wyb, vac, vbc);
            ccol = c1;
        }
        float4 sa = lerp4(vap, vac, wx);
        float4 sb = lerp4(vbp, vbc, wx);
        m0 = max4(m0, max4(sa, sb));
        if (sx & 1) {
            store_nt4(obase + (size_t)(sx >> 1) * CC, m0);
            m0 = make_float4(-INFINITY, -INFINITY, -INFINITY, -INFINITY);
        }
    }
}

__global__ __launch_bounds__(128, 4) void roipool_f_kernel(
    const float* __restrict__ feat, const float* __restrict__ rois,
    const int* __restrict__ im_size, float* __restrict__ out, int N)
{
    int bid = blockIdx.x;
    int n   = bid / POOLD;
    int py  = bid - n * POOLD;
    if (n >= N) return;

    float h = (float)im_size[0];
    float w = (float)im_size[1];
    float4 box = *(const float4*)(rois + 4 * n);
    float ny1 = box.y / h, nx1 = box.x / w;
    float ny2 = box.w / h, nx2 = box.z / w;
    const float inv = 1.0f / (float)(SAMPD - 1);

    float tya = (float)(2 * py) * inv;
    float tyb = (float)(2 * py + 1) * inv;
    float ysa = (ny1 + (ny2 - ny1) * tya) * (float)(HF - 1);
    float ysb = (ny1 + (ny2 - ny1) * tyb) * (float)(HF - 1);
    ysa = fminf(fmaxf(ysa, 0.0f), (float)(HF - 1));
    ysb = fminf(fmaxf(ysb, 0.0f), (float)(HF - 1));
    float y0fa = floorf(ysa), y0fb = floorf(ysb);
    float wya = ysa - y0fa, wyb = ysb - y0fb;
    int iya = __builtin_amdgcn_readfirstlane((int)y0fa);
    int iyb = __builtin_amdgcn_readfirstlane((int)y0fb);
    int iya1 = min(iya + 1, HF - 1);
    int iyb1 = min(iyb + 1, HF - 1);
    int ro0 = iya * (WF * CC), ro1 = iya1 * (WF * CC);
    int ro2 = iyb * (WF * CC), ro3 = iyb1 * (WF * CC);

    const float* pbase = feat + (size_t)threadIdx.x * 4;
    float* obase = out + ((size_t)(n * POOLD + py) * POOLD) * CC + (size_t)threadIdx.x * 4;

    if (ro2 == ro0)      run_row_f<0>(pbase, obase, nx1, nx2, ro0, ro1, ro2, ro3, wya, wyb);
    else if (ro2 == ro1) run_row_f<1>(pbase, obase, nx1, nx2, ro0, ro1, ro2, ro3, wya, wyb);
    else                 run_row_f<2>(pbase, obase, nx1, nx2, ro0, ro1, ro2, ro3, wya, wyb);
}

extern "C" void kernel_launch(void* const* d_in, const int* in_sizes, int n_in,
                              void* d_out, int out_size, void* d_ws, size_t ws_size,
                              hipStream_t stream) {
    const float* feat    = (const float*)d_in[0];   // [1,37,50,512]
    const float* rois    = (const float*)d_in[1];   // [N,4]
    const int*   im_size = (const int*)d_in[2];     // [2]
    float* out = (float*)d_out;

    int N = in_sizes[1] / 4;
    int nblocks = N * POOLD;

    const size_t need = (size_t)HF * WF * CC * sizeof(_Float16);  // 1,894,400 B
    if (d_ws != nullptr && ws_size >= need) {
        _Float16* hbuf = (_Float16*)d_ws;
        int total8 = (HF * WF * CC) / 8;  // 118400
        cvt_kernel<<<(total8 + 255) / 256, 256, 0, stream>>>(feat, hbuf, total8);
        roipool_h_kernel<<<nblocks, 64, 0, stream>>>(hbuf, rois, im_size, out, N);
    } else {
        roipool_f_kernel<<<nblocks, 128, 0, stream>>>(feat, rois, im_size, out, N);
    }
}

// Round 6
// 123.375 us; speedup vs baseline: 1.1329x; 1.1329x over previous
//
#include <hip/hip_runtime.h>
#include <math.h>

#define HF 37
#define WF 50
#define CC 512
#define POOLD 7
#define SAMPD 14

typedef float nfloat4 __attribute__((ext_vector_type(4)));

__device__ __forceinline__ float4 lerp4(float4 a, float4 b, float t) {
    float4 r;
    r.x = a.x + t * (b.x - a.x);
    r.y = a.y + t * (b.y - a.y);
    r.z = a.z + t * (b.z - a.z);
    r.w = a.w + t * (b.w - a.w);
    return r;
}

__device__ __forceinline__ float4 max4(float4 a, float4 b) {
    float4 r;
    r.x = fmaxf(a.x, b.x);
    r.y = fmaxf(a.y, b.y);
    r.z = fmaxf(a.z, b.z);
    r.w = fmaxf(a.w, b.w);
    return r;
}

__device__ __forceinline__ void store_nt4(float* p, float4 v) {
    nfloat4 nv;
    nv.x = v.x; nv.y = v.y; nv.z = v.z; nv.w = v.w;
    __builtin_nontemporal_store(nv, (nfloat4*)p);
}

// Load one feature column and vertically reduce to the two sample rows.
// RC (fixed per block): 0 -> both samples use the same row pair (2 loads);
// 1 -> middle row shared (3 loads); 2 -> general (4 loads).
template <int RC>
__device__ __forceinline__ void loadcol(const float* __restrict__ pbase, int col,
                                        int ro0, int ro1, int ro2, int ro3,
                                        float wya, float wyb,
                                        float4& va, float4& vb) {
    const float* p = pbase + (size_t)col * CC;
    if (RC == 0) {
        float4 rA = *(const float4*)(p + ro0);
        float4 rB = *(const float4*)(p + ro1);
        va = lerp4(rA, rB, wya);
        vb = lerp4(rA, rB, wyb);
    } else if (RC == 1) {
        float4 rA = *(const float4*)(p + ro0);
        float4 rB = *(const float4*)(p + ro1);
        float4 rC = *(const float4*)(p + ro3);
        va = lerp4(rA, rB, wya);
        vb = lerp4(rB, rC, wyb);
    } else {
        float4 r0 = *(const float4*)(p + ro0);
        float4 r1 = *(const float4*)(p + ro1);
        float4 r2 = *(const float4*)(p + ro2);
        float4 r3 = *(const float4*)(p + ro3);
        va = lerp4(r0, r1, wya);
        vb = lerp4(r2, r3, wyb);
    }
}

template <int RC>
__device__ __forceinline__ void run_row(const float* __restrict__ pbase,
                                        float* __restrict__ obase,
                                        float xbase, float xscale,
                                        int ro0, int ro1, int ro2, int ro3,
                                        float wya, float wyb) {
    int pcol = -1000, ccol = -1000;
    float4 vap, vbp, vac, vbc;
    float4 m0 = make_float4(-INFINITY, -INFINITY, -INFINITY, -INFINITY);

    // ROLLED loop: keeps live state ~1 iteration -> low VGPR -> high occupancy.
    #pragma unroll 1
    for (int sx = 0; sx < SAMPD; ++sx) {
        float xs = fmaf((float)sx, xscale, xbase);        // premultiplied slope
        xs = fminf(fmaxf(xs, 0.0f), (float)(WF - 1));
        float x0f = floorf(xs);
        float wx = xs - x0f;
        int c0 = __builtin_amdgcn_readfirstlane((int)x0f);
        int c1 = min(c0 + 1, WF - 1);

        if (c0 == ccol) {
            pcol = ccol; vap = vac; vbp = vbc;
            loadcol<RC>(pbase, c1, ro0, ro1, ro2, ro3, wya, wyb, vac, vbc);
            ccol = c1;
        } else if (c0 != pcol) {
            loadcol<RC>(pbase, c0, ro0, ro1, ro2, ro3, wya, wyb, vap, vbp);
            pcol = c0;
            loadcol<RC>(pbase, c1, ro0, ro1, ro2, ro3, wya, wyb, vac, vbc);
            ccol = c1;
        }

        float4 sa = lerp4(vap, vac, wx);
        float4 sb = lerp4(vbp, vbc, wx);
        float4 mm = max4(sa, sb);
        m0 = max4(m0, mm);

        if (sx & 1) {
            store_nt4(obase + (size_t)(sx >> 1) * CC, m0);
            m0 = make_float4(-INFINITY, -INFINITY, -INFINITY, -INFINITY);
        }
    }
}

// One block per (roi, pooled_row). 128 threads * float4 = 512 channels.
// launch_bounds (128, 8): 8 waves/EU cap -> 64-VGPR budget. Kernel needs ~50
// live VGPRs, so this doubles resident waves vs the (128,4) baseline -- the
// occupancy/stall-coverage A/B this round isolates.
__global__ __launch_bounds__(128, 8) void roipool_kernel(
    const float* __restrict__ feat,    // [HF, WF, CC]
    const float* __restrict__ rois,    // [N, 4] (x1,y1,x2,y2)
    const int*   __restrict__ im_size, // [2] (h, w)
    float*       __restrict__ out,     // [N, 7, 7, CC]
    int N)
{
    int bid = blockIdx.x;
    int n   = bid / POOLD;
    int py  = bid - n * POOLD;
    if (n >= N) return;

    float h = (float)im_size[0];
    float w = (float)im_size[1];
    float4 box = *(const float4*)(rois + 4 * n);
    float ny1 = box.y / h, nx1 = box.x / w;
    float ny2 = box.w / h, nx2 = box.z / w;

    const float inv = 1.0f / (float)(SAMPD - 1);

    // x sampling as xs = sx * xscale + xbase (fewer per-iteration ops)
    float xscale = (nx2 - nx1) * inv * (float)(WF - 1);
    float xbase  = nx1 * (float)(WF - 1);

    // vertical taps for the two sample rows of this pooled row (block-uniform)
    float tya = (float)(2 * py) * inv;
    float tyb = (float)(2 * py + 1) * inv;
    float ysa = (ny1 + (ny2 - ny1) * tya) * (float)(HF - 1);
    float ysb = (ny1 + (ny2 - ny1) * tyb) * (float)(HF - 1);
    ysa = fminf(fmaxf(ysa, 0.0f), (float)(HF - 1));
    ysb = fminf(fmaxf(ysb, 0.0f), (float)(HF - 1));
    float y0fa = floorf(ysa);
    float y0fb = floorf(ysb);
    float wya = ysa - y0fa;
    float wyb = ysb - y0fb;
    int iya = __builtin_amdgcn_readfirstlane((int)y0fa);
    int iyb = __builtin_amdgcn_readfirstlane((int)y0fb);
    int iya1 = min(iya + 1, HF - 1);
    int iyb1 = min(iyb + 1, HF - 1);
    int ro0 = iya  * (WF * CC);
    int ro1 = iya1 * (WF * CC);
    int ro2 = iyb  * (WF * CC);
    int ro3 = iyb1 * (WF * CC);

    const float* pbase = feat + (size_t)threadIdx.x * 4;
    float* obase = out + ((size_t)(n * POOLD + py) * POOLD) * CC + (size_t)threadIdx.x * 4;

    // Row-sharing case is fixed for the whole block -> one scalar dispatch.
    if (ro2 == ro0) {
        run_row<0>(pbase, obase, xbase, xscale, ro0, ro1, ro2, ro3, wya, wyb);
    } else if (ro2 == ro1) {
        run_row<1>(pbase, obase, xbase, xscale, ro0, ro1, ro2, ro3, wya, wyb);
    } else {
        run_row<2>(pbase, obase, xbase, xscale, ro0, ro1, ro2, ro3, wya, wyb);
    }
}

extern "C" void kernel_launch(void* const* d_in, const int* in_sizes, int n_in,
                              void* d_out, int out_size, void* d_ws, size_t ws_size,
                              hipStream_t stream) {
    const float* feat    = (const float*)d_in[0];   // [1,37,50,512]
    const float* rois    = (const float*)d_in[1];   // [N,4]
    const int*   im_size = (const int*)d_in[2];     // [2]
    float* out = (float*)d_out;

    int N = in_sizes[1] / 4;
    int nblocks = N * POOLD;
    roipool_kernel<<<nblocks, 128, 0, stream>>>(feat, rois, im_size, out, N);
}